// Round 2
// baseline (2270.469 us; speedup 1.0000x reference)
//
#include <hip/hip_runtime.h>
#include <hip/hip_bf16.h>
#include <stdint.h>
#include <math.h>

#define T_TOK 4096
#define HD    1024
#define NE    16
#define FF    2816
#define TOPK  8
#define NPAIR (T_TOK*TOPK)

typedef __attribute__((ext_vector_type(8))) __bf16 bf16x8;
typedef __attribute__((ext_vector_type(4))) float  f32x4;

__device__ __forceinline__ unsigned short f2bf(float x){
  union { float f; unsigned u; } c; c.f = x;
  unsigned r = (c.u + 0x7FFFu + ((c.u >> 16) & 1u)) >> 16;
  return (unsigned short)r;
}
__device__ __forceinline__ float bf2f(unsigned short h){
  union { unsigned u; float f; } c; c.u = ((unsigned)h) << 16; return c.f;
}

// async global->LDS, 16B per lane
__device__ __forceinline__ void gload16(const void* src, void* lds_dst){
  __builtin_amdgcn_global_load_lds((const __attribute__((address_space(1))) unsigned int*)src,
                                   (__attribute__((address_space(3))) unsigned int*)lds_dst,
                                   16, 0, 0);
}

// ---------------- fp32 -> bf16 (RNE) conversion ----------------
__global__ __launch_bounds__(256) void convert_bf16_kernel(
    const float* __restrict__ src, unsigned short* __restrict__ dst, int n4)
{
  int i = blockIdx.x * blockDim.x + threadIdx.x;
  int stride = gridDim.x * blockDim.x;
  for (; i < n4; i += stride){
    float4 v = ((const float4*)src)[i];
    ushort4 o;
    o.x = f2bf(v.x); o.y = f2bf(v.y); o.z = f2bf(v.z); o.w = f2bf(v.w);
    ((ushort4*)dst)[i] = o;
  }
}

// ---------------- router ----------------
__global__ __launch_bounds__(256) void router_kernel(
    const float* __restrict__ x, const float* __restrict__ rw,
    unsigned short* __restrict__ xbf, int* __restrict__ topk_idx, float* __restrict__ topk_w)
{
  __shared__ float xs[HD];
  __shared__ float lg[NE];
  const int t   = blockIdx.x;
  const int tid = threadIdx.x;
  const int lane = tid & 63;
  const int wid  = tid >> 6;

  float4 v = ((const float4*)(x + (size_t)t*HD))[tid];
  ((float4*)xs)[tid] = v;
  ushort4 o;
  o.x = f2bf(v.x); o.y = f2bf(v.y); o.z = f2bf(v.z); o.w = f2bf(v.w);
  ((ushort4*)(xbf + (size_t)t*HD))[tid] = o;
  __syncthreads();

  for (int ee = 0; ee < 4; ++ee){
    int e = wid*4 + ee;
    const float* w = rw + (size_t)e*HD;
    float p = 0.f;
    for (int j = lane; j < HD; j += 64) p += xs[j] * w[j];
    #pragma unroll
    for (int offs = 32; offs; offs >>= 1) p += __shfl_xor(p, offs, 64);
    if (lane == 0) lg[e] = p;
  }
  __syncthreads();

  if (tid == 0){
    float vals[NE];
    #pragma unroll
    for (int e = 0; e < NE; ++e) vals[e] = lg[e];
    int   idx[TOPK]; float tv[TOPK];
    for (int k = 0; k < TOPK; ++k){
      int bi = 0; float bv = -3.4e38f;
      for (int e = 0; e < NE; ++e) if (vals[e] > bv){ bv = vals[e]; bi = e; }
      idx[k] = bi; tv[k] = bv; vals[bi] = -3.4e38f;
    }
    float m = tv[0];
    float ex[TOPK]; float s = 0.f;
    for (int k = 0; k < TOPK; ++k){ ex[k] = expf(tv[k] - m); s += ex[k]; }
    float inv = 1.f / s;
    for (int k = 0; k < TOPK; ++k){
      topk_idx[t*TOPK + k] = idx[k];
      topk_w [t*TOPK + k] = ex[k] * inv;
    }
  }
}

// ---------------- per-expert counts ----------------
__global__ __launch_bounds__(256) void count_kernel(
    const int* __restrict__ topk_idx, int* __restrict__ cnt)
{
  const int e = blockIdx.x;
  const int tid = threadIdx.x;
  __shared__ int wc[4];
  int c = 0;
  for (int t = tid; t < T_TOK; t += 256){
    bool f = false;
    #pragma unroll
    for (int k = 0; k < TOPK; ++k) f |= (topk_idx[t*TOPK + k] == e);
    c += f ? 1 : 0;
  }
  #pragma unroll
  for (int offs = 32; offs; offs >>= 1) c += __shfl_xor(c, offs, 64);
  if ((tid & 63) == 0) wc[tid >> 6] = c;
  __syncthreads();
  if (tid == 0) cnt[e] = wc[0] + wc[1] + wc[2] + wc[3];
}

// ---------------- deterministic compacted token lists per expert ----------------
__global__ __launch_bounds__(256) void lists_kernel(
    const int* __restrict__ topk_idx, const int* __restrict__ cnt,
    int* __restrict__ rows, int* __restrict__ slot_of, int* __restrict__ offs_out)
{
  const int e = blockIdx.x;
  const int tid = threadIdx.x;
  const int lane = tid & 63;
  const int wid  = tid >> 6;
  int off = 0;
  for (int i = 0; i < e; ++i) off += cnt[i];
  if (tid == 0) offs_out[e] = off;

  __shared__ int wc[4];
  int base = 0;
  for (int c0 = 0; c0 < T_TOK; c0 += 256){
    int t = c0 + tid;
    int kpos = -1;
    #pragma unroll
    for (int k = 0; k < TOPK; ++k) if (topk_idx[t*TOPK + k] == e) kpos = k;
    bool f = (kpos >= 0);
    unsigned long long m = __ballot(f);
    if (lane == 0) wc[wid] = __popcll(m);
    __syncthreads();
    int p = base;
    for (int w = 0; w < wid; ++w) p += wc[w];
    p += __popcll(m & ((1ULL << lane) - 1ULL));
    if (f){
      rows[off + p] = t;
      slot_of[t*TOPK + kpos] = off + p;
    }
    int tot = wc[0] + wc[1] + wc[2] + wc[3];
    __syncthreads();
    base += tot;
  }
}

// ---------------- grouped GEMM: C[off_e+r][col] = A_rows x B_e^T ----------------
// BM=BN=128, BK=64, 4 waves (2Mx2N, wave tile 64x64), depth-2 pipeline,
// counted vmcnt(8), raw s_barrier, XOR-swizzled LDS (slot ^= row&7).
// GATHER: A row indices via rows[] (stage-1) or contiguous off_e+r (stage-2).
// EPI: 0 = plain bf16 store; 1 = h = silu(g_from_C) * acc, stored in place.
template<int GATHER, int EPI>
__global__ __launch_bounds__(256, 2) void grouped_gemm(
    const unsigned short* __restrict__ A,   // [*][lda] bf16
    const unsigned short* __restrict__ B,   // + e*eBstride -> [N][ldb] bf16
    unsigned short* __restrict__ C,         // [NPAIR][ldc] bf16
    const int* __restrict__ rows, const int* __restrict__ cnt, const int* __restrict__ offs,
    int lda, int ldb, int ldc, size_t eBstride, int NT)
{
  const int e  = blockIdx.z;
  const int c  = cnt[e];
  const int m0 = blockIdx.x * 128;
  if (m0 >= c) return;
  const int n0 = blockIdx.y * 128;
  const int off_e = offs[e];

  __shared__ unsigned short As[2][8192];   // [buf][128 rows][64 shorts] swizzled
  __shared__ unsigned short Bs[2][8192];

  const int tid  = threadIdx.x;
  const int lane = tid & 63;
  const int wid  = tid >> 6;
  const int ar = lane & 15;
  const int kb = lane >> 4;
  const int wm = wid >> 1;
  const int wn = wid & 1;

  // staging sources: chunk c = j*256+tid -> row c>>3, phys slot c&7.
  // phys slot sl holds logical slot sl^(row&7)  (pre-swizzled source, linear LDS dest)
  const unsigned short* asrc[4];
  const unsigned short* bsrc[4];
  #pragma unroll
  for (int j = 0; j < 4; ++j){
    int cj = j*256 + tid;
    int r  = cj >> 3;
    int sw = ((cj & 7) ^ (r & 7)) * 8;
    int rm = m0 + r; if (rm > c-1) rm = c-1;
    size_t arow = GATHER ? (size_t)rows[off_e + rm] : (size_t)(off_e + rm);
    asrc[j] = A + arow*lda + sw;
    bsrc[j] = B + (size_t)e*eBstride + (size_t)(n0 + r)*ldb + sw;
  }

  #define STAGE(T, BUF) do { \
    _Pragma("unroll") \
    for (int j = 0; j < 4; ++j){ \
      int cj = j*256 + tid; \
      gload16(asrc[j] + (T)*64, &As[BUF][cj*8]); \
      gload16(bsrc[j] + (T)*64, &Bs[BUF][cj*8]); \
    } \
  } while(0)

  STAGE(0, 0);
  STAGE(1, 1);

  f32x4 acc[4][4] = {};

  for (int t = 0; t < NT; ++t){
    asm volatile("s_waitcnt vmcnt(8)" ::: "memory");   // tile t landed; t+1 in flight
    __builtin_amdgcn_sched_barrier(0);
    __builtin_amdgcn_s_barrier();                      // all waves' stages for t visible
    __builtin_amdgcn_sched_barrier(0);
    const int b = t & 1;
    #pragma unroll
    for (int kk = 0; kk < 2; ++kk){
      bf16x8 pa[4], pb[4];
      #pragma unroll
      for (int m = 0; m < 4; ++m){
        int r = wm*64 + m*16 + ar;
        pa[m] = *(const bf16x8*)&As[b][r*64 + (((kk*4 + kb) ^ (r & 7))*8)];
      }
      #pragma unroll
      for (int n = 0; n < 4; ++n){
        int r = wn*64 + n*16 + ar;
        pb[n] = *(const bf16x8*)&Bs[b][r*64 + (((kk*4 + kb) ^ (r & 7))*8)];
      }
      #pragma unroll
      for (int m = 0; m < 4; ++m){
        #pragma unroll
        for (int n = 0; n < 4; ++n){
          acc[m][n] = __builtin_amdgcn_mfma_f32_16x16x32_bf16(pa[m], pb[n], acc[m][n], 0, 0, 0);
        }
      }
    }
    __builtin_amdgcn_sched_barrier(0);
    __builtin_amdgcn_s_barrier();                      // all waves done reading buf b
    __builtin_amdgcn_sched_barrier(0);
    int tn = t + 2; if (tn > NT-1) tn = NT-1;          // clamp: keep vmcnt count uniform
    STAGE(tn, b);
  }
  asm volatile("s_waitcnt vmcnt(0)" ::: "memory");     // drain before LDS dealloc/stores
  #undef STAGE

  #pragma unroll
  for (int m = 0; m < 4; ++m){
    int gm = m0 + wm*64 + m*16 + kb*4;
    #pragma unroll
    for (int n = 0; n < 4; ++n){
      int col = n0 + wn*64 + n*16 + ar;
      #pragma unroll
      for (int i = 0; i < 4; ++i){
        int r = gm + i;
        if (r < c){
          size_t idx = (size_t)(off_e + r)*ldc + col;
          if (EPI == 1){
            float g = bf2f(C[idx]);
            float s = g / (1.0f + expf(-g));
            C[idx] = f2bf(s * acc[m][n][i]);
          } else {
            C[idx] = f2bf(acc[m][n][i]);
          }
        }
      }
    }
  }
}

// ---------------- combine: out[t] = sum_k w_k * y[slot_of[t,k]] ----------------
__global__ __launch_bounds__(256) void combine_kernel(
    const unsigned short* __restrict__ ybuf,
    const int* __restrict__ slot_of, const float* __restrict__ topk_w,
    float* __restrict__ out)
{
  const int t   = blockIdx.x;
  const int tid = threadIdx.x;
  const int c0  = tid * 4;
  float4 acc = {0.f, 0.f, 0.f, 0.f};
  #pragma unroll
  for (int k = 0; k < TOPK; ++k){
    int slot = slot_of[t*TOPK + k];
    float w  = topk_w[t*TOPK + k];
    ushort4 v = *(const ushort4*)&ybuf[(size_t)slot*HD + c0];
    acc.x += w * bf2f(v.x);
    acc.y += w * bf2f(v.y);
    acc.z += w * bf2f(v.z);
    acc.w += w * bf2f(v.w);
  }
  ((float4*)out)[(size_t)t*(HD/4) + tid] = acc;
}

extern "C" void kernel_launch(void* const* d_in, const int* in_sizes, int n_in,
                              void* d_out, int out_size, void* d_ws, size_t ws_size,
                              hipStream_t stream)
{
  const float* x  = (const float*)d_in[0];
  const float* rw = (const float*)d_in[1];
  const float* gw = (const float*)d_in[2];
  const float* uw = (const float*)d_in[3];
  const float* dw = (const float*)d_in[4];
  float* out = (float*)d_out;

  char* ws = (char*)d_ws;
  size_t off = 0;
  auto alloc = [&](size_t b) -> void* {
    void* p = ws + off;
    off += (b + 255) & ~(size_t)255;
    return p;
  };

  unsigned short* gwb  = (unsigned short*)alloc((size_t)NE*FF*HD*2);
  unsigned short* uwb  = (unsigned short*)alloc((size_t)NE*FF*HD*2);
  unsigned short* dwb  = (unsigned short*)alloc((size_t)NE*HD*FF*2);
  unsigned short* xbf  = (unsigned short*)alloc((size_t)T_TOK*HD*2);
  unsigned short* gbuf = (unsigned short*)alloc((size_t)NPAIR*FF*2);   // g -> h (in place)
  unsigned short* ybuf = (unsigned short*)alloc((size_t)NPAIR*HD*2);
  int*   tki   = (int*)alloc((size_t)T_TOK*TOPK*4);
  float* tkw   = (float*)alloc((size_t)T_TOK*TOPK*4);
  int*   rowsb = (int*)alloc((size_t)NPAIR*4);
  int*   slotf = (int*)alloc((size_t)NPAIR*4);
  int*   cntb  = (int*)alloc(NE*4);
  int*   offsb = (int*)alloc(NE*4);

  const int n4 = NE*FF*HD/4;
  convert_bf16_kernel<<<4096, 256, 0, stream>>>(gw, gwb, n4);
  convert_bf16_kernel<<<4096, 256, 0, stream>>>(uw, uwb, n4);
  convert_bf16_kernel<<<4096, 256, 0, stream>>>(dw, dwb, n4);

  router_kernel<<<T_TOK, 256, 0, stream>>>(x, rw, xbf, tki, tkw);
  count_kernel<<<NE, 256, 0, stream>>>(tki, cntb);
  lists_kernel<<<NE, 256, 0, stream>>>(tki, cntb, rowsb, slotf, offsb);

  // stage-1a: g = x @ gate^T        (gather A rows, plain store)
  grouped_gemm<1,0><<<dim3(32, FF/128, NE), 256, 0, stream>>>(
      xbf, gwb, gbuf, rowsb, cntb, offsb, HD, HD, FF, (size_t)FF*HD, HD/64);
  // stage-1b: h = silu(g) * (x @ up^T)   (gather A rows, fused epilogue, in-place on gbuf)
  grouped_gemm<1,1><<<dim3(32, FF/128, NE), 256, 0, stream>>>(
      xbf, uwb, gbuf, rowsb, cntb, offsb, HD, HD, FF, (size_t)FF*HD, HD/64);
  // stage-2: y = h @ down^T          (contiguous A rows, plain store)
  grouped_gemm<0,0><<<dim3(32, HD/128, NE), 256, 0, stream>>>(
      gbuf, dwb, ybuf, rowsb, cntb, offsb, FF, FF, HD, (size_t)HD*FF, FF/64);

  combine_kernel<<<T_TOK, 256, 0, stream>>>(ybuf, slotf, tkw, out);
}

// Round 3
// 856.973 us; speedup vs baseline: 2.6494x; 2.6494x over previous
//
#include <hip/hip_runtime.h>
#include <hip/hip_bf16.h>
#include <stdint.h>
#include <math.h>

#define T_TOK 4096
#define HD    1024
#define NE    16
#define FF    2816
#define TOPK  8
#define NPAIR (T_TOK*TOPK)

typedef __attribute__((ext_vector_type(8))) __bf16 bf16x8;
typedef __attribute__((ext_vector_type(4))) float  f32x4;

__device__ __forceinline__ unsigned short f2bf(float x){
  union { float f; unsigned u; } c; c.f = x;
  unsigned r = (c.u + 0x7FFFu + ((c.u >> 16) & 1u)) >> 16;
  return (unsigned short)r;
}
__device__ __forceinline__ float bf2f(unsigned short h){
  union { unsigned u; float f; } c; c.u = ((unsigned)h) << 16; return c.f;
}

// async global->LDS, 16B per lane
__device__ __forceinline__ void gload16(const void* src, void* lds_dst){
  __builtin_amdgcn_global_load_lds((const __attribute__((address_space(1))) unsigned int*)src,
                                   (__attribute__((address_space(3))) unsigned int*)lds_dst,
                                   16, 0, 0);
}

// ---------------- fp32 -> bf16 (RNE) conversion ----------------
__global__ __launch_bounds__(256) void convert_bf16_kernel(
    const float* __restrict__ src, unsigned short* __restrict__ dst, int n4)
{
  int i = blockIdx.x * blockDim.x + threadIdx.x;
  int stride = gridDim.x * blockDim.x;
  for (; i < n4; i += stride){
    float4 v = ((const float4*)src)[i];
    ushort4 o;
    o.x = f2bf(v.x); o.y = f2bf(v.y); o.z = f2bf(v.z); o.w = f2bf(v.w);
    ((ushort4*)dst)[i] = o;
  }
}

// ---------------- router ----------------
__global__ __launch_bounds__(256) void router_kernel(
    const float* __restrict__ x, const float* __restrict__ rw,
    unsigned short* __restrict__ xbf, int* __restrict__ topk_idx, float* __restrict__ topk_w)
{
  __shared__ float xs[HD];
  __shared__ float lg[NE];
  const int t   = blockIdx.x;
  const int tid = threadIdx.x;
  const int lane = tid & 63;
  const int wid  = tid >> 6;

  float4 v = ((const float4*)(x + (size_t)t*HD))[tid];
  ((float4*)xs)[tid] = v;
  ushort4 o;
  o.x = f2bf(v.x); o.y = f2bf(v.y); o.z = f2bf(v.z); o.w = f2bf(v.w);
  ((ushort4*)(xbf + (size_t)t*HD))[tid] = o;
  __syncthreads();

  for (int ee = 0; ee < 4; ++ee){
    int e = wid*4 + ee;
    const float* w = rw + (size_t)e*HD;
    float p = 0.f;
    for (int j = lane; j < HD; j += 64) p += xs[j] * w[j];
    #pragma unroll
    for (int offs = 32; offs; offs >>= 1) p += __shfl_xor(p, offs, 64);
    if (lane == 0) lg[e] = p;
  }
  __syncthreads();

  if (tid == 0){
    float vals[NE];
    #pragma unroll
    for (int e = 0; e < NE; ++e) vals[e] = lg[e];
    int   idx[TOPK]; float tv[TOPK];
    for (int k = 0; k < TOPK; ++k){
      int bi = 0; float bv = -3.4e38f;
      for (int e = 0; e < NE; ++e) if (vals[e] > bv){ bv = vals[e]; bi = e; }
      idx[k] = bi; tv[k] = bv; vals[bi] = -3.4e38f;
    }
    float m = tv[0];
    float ex[TOPK]; float s = 0.f;
    for (int k = 0; k < TOPK; ++k){ ex[k] = expf(tv[k] - m); s += ex[k]; }
    float inv = 1.f / s;
    for (int k = 0; k < TOPK; ++k){
      topk_idx[t*TOPK + k] = idx[k];
      topk_w [t*TOPK + k] = ex[k] * inv;
    }
  }
}

// ---------------- per-expert counts ----------------
__global__ __launch_bounds__(256) void count_kernel(
    const int* __restrict__ topk_idx, int* __restrict__ cnt)
{
  const int e = blockIdx.x;
  const int tid = threadIdx.x;
  __shared__ int wc[4];
  int c = 0;
  for (int t = tid; t < T_TOK; t += 256){
    bool f = false;
    #pragma unroll
    for (int k = 0; k < TOPK; ++k) f |= (topk_idx[t*TOPK + k] == e);
    c += f ? 1 : 0;
  }
  #pragma unroll
  for (int offs = 32; offs; offs >>= 1) c += __shfl_xor(c, offs, 64);
  if ((tid & 63) == 0) wc[tid >> 6] = c;
  __syncthreads();
  if (tid == 0) cnt[e] = wc[0] + wc[1] + wc[2] + wc[3];
}

// ---------------- deterministic compacted token lists per expert ----------------
__global__ __launch_bounds__(256) void lists_kernel(
    const int* __restrict__ topk_idx, const int* __restrict__ cnt,
    int* __restrict__ rows, int* __restrict__ slot_of, int* __restrict__ offs_out)
{
  const int e = blockIdx.x;
  const int tid = threadIdx.x;
  const int lane = tid & 63;
  const int wid  = tid >> 6;
  int off = 0;
  for (int i = 0; i < e; ++i) off += cnt[i];
  if (tid == 0) offs_out[e] = off;

  __shared__ int wc[4];
  int base = 0;
  for (int c0 = 0; c0 < T_TOK; c0 += 256){
    int t = c0 + tid;
    int kpos = -1;
    #pragma unroll
    for (int k = 0; k < TOPK; ++k) if (topk_idx[t*TOPK + k] == e) kpos = k;
    bool f = (kpos >= 0);
    unsigned long long m = __ballot(f);
    if (lane == 0) wc[wid] = __popcll(m);
    __syncthreads();
    int p = base;
    for (int w = 0; w < wid; ++w) p += wc[w];
    p += __popcll(m & ((1ULL << lane) - 1ULL));
    if (f){
      rows[off + p] = t;
      slot_of[t*TOPK + kpos] = off + p;
    }
    int tot = wc[0] + wc[1] + wc[2] + wc[3];
    __syncthreads();
    base += tot;
  }
}

// ---------------- stage-1: h = silu(x@gateT) * (x@upT), grouped ----------------
// BM=128 (tokens) x BF=64, BK=64, 4 waves (2Mx2F, wave 64x32 each for g and u),
// single-buffered LDS (32KB, 3 blocks/CU), m97-style 2-barrier loop,
// XOR-swizzled LDS rows (bank-conflict-free ds_read_b128).
__global__ __launch_bounds__(256, 3) void gemm_gateup(
    const unsigned short* __restrict__ xbf,
    const unsigned short* __restrict__ gw,
    const unsigned short* __restrict__ uw,
    const int* __restrict__ rows, const int* __restrict__ cnt, const int* __restrict__ offs,
    unsigned short* __restrict__ hbuf)
{
  // 1D grid = 32 * (FF/64) * NE, bijective XCD swizzle (grid % 8 == 0)
  const int cpx = gridDim.x >> 3;
  const int bid = blockIdx.x;
  const int nid = (bid & 7) * cpx + (bid >> 3);
  const int mb   = nid & 31;
  const int rest = nid >> 5;
  const int nb   = rest % (FF/64);
  const int e    = rest / (FF/64);

  const int c  = cnt[e];
  const int m0 = mb * 128;
  if (m0 >= c) return;
  const int n0 = nb * 64;
  const int off_e = offs[e];

  __shared__ unsigned short As[128*64];
  __shared__ unsigned short Bg[64*64];
  __shared__ unsigned short Bu[64*64];

  const int tid  = threadIdx.x;
  const int lane = tid & 63;
  const int wid  = tid >> 6;
  const int ar = lane & 15;
  const int kb = lane >> 4;
  const int wm = wid >> 1;
  const int wn = wid & 1;

  // chunk c = j*256+tid -> row c>>3, phys slot c&7; phys slot holds logical (c&7)^(row&7)
  const unsigned short* asrc[4];
  #pragma unroll
  for (int j = 0; j < 4; ++j){
    int cj = j*256 + tid;
    int r  = cj >> 3;
    int sw = ((cj & 7) ^ (r & 7)) * 8;
    int rm = m0 + r; if (rm > c-1) rm = c-1;
    asrc[j] = xbf + (size_t)rows[off_e + rm]*HD + sw;
  }
  const unsigned short* bgsrc[2];
  const unsigned short* busrc[2];
  #pragma unroll
  for (int j = 0; j < 2; ++j){
    int cj = j*256 + tid;
    int r  = cj >> 3;
    int sw = ((cj & 7) ^ (r & 7)) * 8;
    bgsrc[j] = gw + ((size_t)e*FF + n0 + r)*HD + sw;
    busrc[j] = uw + ((size_t)e*FF + n0 + r)*HD + sw;
  }

  f32x4 accg[4][2] = {};
  f32x4 accu[4][2] = {};

  for (int ks = 0; ks < HD/64; ++ks){
    #pragma unroll
    for (int j = 0; j < 4; ++j)
      gload16(asrc[j] + ks*64, &As[(j*256+tid)*8]);
    #pragma unroll
    for (int j = 0; j < 2; ++j){
      gload16(bgsrc[j] + ks*64, &Bg[(j*256+tid)*8]);
      gload16(busrc[j] + ks*64, &Bu[(j*256+tid)*8]);
    }
    __syncthreads();
    #pragma unroll
    for (int kk = 0; kk < 2; ++kk){
      bf16x8 a[4], fg[2], fu[2];
      #pragma unroll
      for (int m = 0; m < 4; ++m){
        int r = wm*64 + m*16 + ar;
        a[m] = *(const bf16x8*)&As[r*64 + (((kk*4 + kb) ^ (r & 7))*8)];
      }
      #pragma unroll
      for (int n = 0; n < 2; ++n){
        int rf = wn*32 + n*16 + ar;
        int o  = rf*64 + (((kk*4 + kb) ^ (rf & 7))*8);
        fg[n] = *(const bf16x8*)&Bg[o];
        fu[n] = *(const bf16x8*)&Bu[o];
      }
      #pragma unroll
      for (int m = 0; m < 4; ++m){
        #pragma unroll
        for (int n = 0; n < 2; ++n){
          accg[m][n] = __builtin_amdgcn_mfma_f32_16x16x32_bf16(a[m], fg[n], accg[m][n], 0, 0, 0);
          accu[m][n] = __builtin_amdgcn_mfma_f32_16x16x32_bf16(a[m], fu[n], accu[m][n], 0, 0, 0);
        }
      }
    }
    __syncthreads();
  }

  #pragma unroll
  for (int m = 0; m < 4; ++m){
    #pragma unroll
    for (int n = 0; n < 2; ++n){
      int fcol = n0 + wn*32 + n*16 + ar;
      #pragma unroll
      for (int i = 0; i < 4; ++i){
        int gr = m0 + wm*64 + m*16 + kb*4 + i;
        if (gr < c){
          float g = accg[m][n][i];
          float u = accu[m][n][i];
          float s = g / (1.0f + expf(-g));
          hbuf[(size_t)(off_e + gr)*FF + fcol] = f2bf(s * u);
        }
      }
    }
  }
}

// ---------------- stage-2: y = h @ downT, grouped ----------------
// BM=128 x BN=128, BK=64, 4 waves (2x2, wave 64x64), same structure.
__global__ __launch_bounds__(256, 3) void gemm_down(
    const unsigned short* __restrict__ hbuf,
    const unsigned short* __restrict__ dw,
    const int* __restrict__ cnt, const int* __restrict__ offs,
    unsigned short* __restrict__ ybuf)
{
  // 1D grid = 32 * (HD/128) * NE = 4096, XCD swizzle
  const int cpx = gridDim.x >> 3;
  const int bid = blockIdx.x;
  const int nid = (bid & 7) * cpx + (bid >> 3);
  const int mb   = nid & 31;
  const int rest = nid >> 5;
  const int nb   = rest & 7;
  const int e    = rest >> 3;

  const int c  = cnt[e];
  const int m0 = mb * 128;
  if (m0 >= c) return;
  const int n0 = nb * 128;
  const int off_e = offs[e];

  __shared__ unsigned short As[128*64];
  __shared__ unsigned short Bs[128*64];

  const int tid  = threadIdx.x;
  const int lane = tid & 63;
  const int wid  = tid >> 6;
  const int ar = lane & 15;
  const int kb = lane >> 4;
  const int wm = wid >> 1;
  const int wn = wid & 1;

  const unsigned short* asrc[4];
  const unsigned short* bsrc[4];
  #pragma unroll
  for (int j = 0; j < 4; ++j){
    int cj = j*256 + tid;
    int r  = cj >> 3;
    int sw = ((cj & 7) ^ (r & 7)) * 8;
    int rm = m0 + r; if (rm > c-1) rm = c-1;
    asrc[j] = hbuf + (size_t)(off_e + rm)*FF + sw;
    bsrc[j] = dw + ((size_t)e*HD + n0 + r)*FF + sw;
  }

  f32x4 acc[4][4] = {};

  for (int ks = 0; ks < FF/64; ++ks){
    #pragma unroll
    for (int j = 0; j < 4; ++j){
      gload16(asrc[j] + ks*64, &As[(j*256+tid)*8]);
      gload16(bsrc[j] + ks*64, &Bs[(j*256+tid)*8]);
    }
    __syncthreads();
    #pragma unroll
    for (int kk = 0; kk < 2; ++kk){
      bf16x8 a[4], b[4];
      #pragma unroll
      for (int m = 0; m < 4; ++m){
        int r = wm*64 + m*16 + ar;
        a[m] = *(const bf16x8*)&As[r*64 + (((kk*4 + kb) ^ (r & 7))*8)];
      }
      #pragma unroll
      for (int n = 0; n < 4; ++n){
        int r = wn*64 + n*16 + ar;
        b[n] = *(const bf16x8*)&Bs[r*64 + (((kk*4 + kb) ^ (r & 7))*8)];
      }
      #pragma unroll
      for (int m = 0; m < 4; ++m){
        #pragma unroll
        for (int n = 0; n < 4; ++n){
          acc[m][n] = __builtin_amdgcn_mfma_f32_16x16x32_bf16(a[m], b[n], acc[m][n], 0, 0, 0);
        }
      }
    }
    __syncthreads();
  }

  #pragma unroll
  for (int m = 0; m < 4; ++m){
    #pragma unroll
    for (int n = 0; n < 4; ++n){
      int col = n0 + wn*64 + n*16 + ar;
      #pragma unroll
      for (int i = 0; i < 4; ++i){
        int gr = m0 + wm*64 + m*16 + kb*4 + i;
        if (gr < c){
          ybuf[(size_t)(off_e + gr)*HD + col] = f2bf(acc[m][n][i]);
        }
      }
    }
  }
}

// ---------------- combine ----------------
__global__ __launch_bounds__(256) void combine_kernel(
    const unsigned short* __restrict__ ybuf,
    const int* __restrict__ slot_of, const float* __restrict__ topk_w,
    float* __restrict__ out)
{
  const int t   = blockIdx.x;
  const int tid = threadIdx.x;
  const int c0  = tid * 4;
  float4 acc = {0.f, 0.f, 0.f, 0.f};
  #pragma unroll
  for (int k = 0; k < TOPK; ++k){
    int slot = slot_of[t*TOPK + k];
    float w  = topk_w[t*TOPK + k];
    ushort4 v = *(const ushort4*)&ybuf[(size_t)slot*HD + c0];
    acc.x += w * bf2f(v.x);
    acc.y += w * bf2f(v.y);
    acc.z += w * bf2f(v.z);
    acc.w += w * bf2f(v.w);
  }
  ((float4*)out)[(size_t)t*(HD/4) + tid] = acc;
}

extern "C" void kernel_launch(void* const* d_in, const int* in_sizes, int n_in,
                              void* d_out, int out_size, void* d_ws, size_t ws_size,
                              hipStream_t stream)
{
  const float* x  = (const float*)d_in[0];
  const float* rw = (const float*)d_in[1];
  const float* gw = (const float*)d_in[2];
  const float* uw = (const float*)d_in[3];
  const float* dw = (const float*)d_in[4];
  float* out = (float*)d_out;

  char* ws = (char*)d_ws;
  size_t off = 0;
  auto alloc = [&](size_t b) -> void* {
    void* p = ws + off;
    off += (b + 255) & ~(size_t)255;
    return p;
  };

  unsigned short* gwb  = (unsigned short*)alloc((size_t)NE*FF*HD*2);
  unsigned short* uwb  = (unsigned short*)alloc((size_t)NE*FF*HD*2);
  unsigned short* dwb  = (unsigned short*)alloc((size_t)NE*HD*FF*2);
  unsigned short* xbf  = (unsigned short*)alloc((size_t)T_TOK*HD*2);
  unsigned short* hbuf = (unsigned short*)alloc((size_t)NPAIR*FF*2);
  unsigned short* ybuf = (unsigned short*)alloc((size_t)NPAIR*HD*2);
  int*   tki   = (int*)alloc((size_t)T_TOK*TOPK*4);
  float* tkw   = (float*)alloc((size_t)T_TOK*TOPK*4);
  int*   rowsb = (int*)alloc((size_t)NPAIR*4);
  int*   slotf = (int*)alloc((size_t)NPAIR*4);
  int*   cntb  = (int*)alloc(NE*4);
  int*   offsb = (int*)alloc(NE*4);

  const int n4 = NE*FF*HD/4;
  convert_bf16_kernel<<<4096, 256, 0, stream>>>(gw, gwb, n4);
  convert_bf16_kernel<<<4096, 256, 0, stream>>>(uw, uwb, n4);
  convert_bf16_kernel<<<4096, 256, 0, stream>>>(dw, dwb, n4);

  router_kernel<<<T_TOK, 256, 0, stream>>>(x, rw, xbf, tki, tkw);
  count_kernel<<<NE, 256, 0, stream>>>(tki, cntb);
  lists_kernel<<<NE, 256, 0, stream>>>(tki, cntb, rowsb, slotf, offsb);

  gemm_gateup<<<32*(FF/64)*NE, 256, 0, stream>>>(xbf, gwb, uwb, rowsb, cntb, offsb, hbuf);
  gemm_down<<<32*(HD/128)*NE, 256, 0, stream>>>(hbuf, dwb, cntb, offsb, ybuf);

  combine_kernel<<<T_TOK, 256, 0, stream>>>(ybuf, slotf, tkw, out);
}